// Round 8
// baseline (697.720 us; speedup 1.0000x reference)
//
#include <hip/hip_runtime.h>
#include <cstdint>
#include <cstddef>

typedef unsigned short u16;
typedef unsigned char u8;
typedef __attribute__((ext_vector_type(4))) float f32x4;
typedef __attribute__((ext_vector_type(4))) int i32x4;
typedef __attribute__((ext_vector_type(8))) int i32x8;

__device__ inline float bf2f(u16 u) { return __uint_as_float(((unsigned)u) << 16); }
__device__ inline unsigned f2bf(float f) {
  unsigned u = __float_as_uint(f);
  u += 0x7fffu + ((u >> 16) & 1u);   // RNE
  return u >> 16;
}

// f32 -> OCP e4m3fn (RNE). Caller guarantees |f| <= 448.
__device__ inline unsigned f2fp8(float f) {
  unsigned s = (__float_as_uint(f) >> 31) << 7;
  float a = fabsf(f);
  if (a >= 0.015625f) {              // normal range
    unsigned u = __float_as_uint(a);
    u += 0x7FFFFu + ((u >> 20) & 1u);
    unsigned e = (u >> 23) - 120u;   // e32 - 127 + 7
    unsigned m = (u >> 20) & 7u;
    return s | (e << 3) | m;
  }
  int m = (int)rintf(a * 512.0f);    // subnormal step 2^-9 (m=8 rolls to min normal)
  return s | (unsigned)m;
}

// OCP e4m3fn -> f32 (branchless-ish decode; subnormal step 2^-9)
__device__ inline float fp82f(unsigned b) {
  unsigned em = b & 0x7fu;
  float v = (em >= 8u)
      ? __uint_as_float((((em >> 3) + 120u) << 23) | ((em & 7u) << 20))
      : (float)em * 0.001953125f;
  return (b & 0x80u) ? -v : v;
}

__device__ inline void unpack8f8(uint2 q, float* o) {
  o[0] = fp82f(q.x & 255u);  o[1] = fp82f((q.x >> 8) & 255u);
  o[2] = fp82f((q.x >> 16) & 255u);  o[3] = fp82f(q.x >> 24);
  o[4] = fp82f(q.y & 255u);  o[5] = fp82f((q.y >> 8) & 255u);
  o[6] = fp82f((q.y >> 16) & 255u);  o[7] = fp82f(q.y >> 24);
}

__device__ inline void async16(const void* g, void* l) {
  __builtin_amdgcn_global_load_lds(
      (const __attribute__((address_space(1))) void*)g,
      (__attribute__((address_space(3))) void*)l, 16, 0, 0);
}

__device__ inline i32x8 join8(i32x4 lo, i32x4 hi) {
  i32x8 r;
  r[0] = lo[0]; r[1] = lo[1]; r[2] = lo[2]; r[3] = lo[3];
  r[4] = hi[0]; r[5] = hi[1]; r[6] = hi[2]; r[7] = hi[3];
  return r;
}

__device__ inline float fast_sigmoid(float z) {
  return 1.0f / (1.0f + exp2f(-1.4426950408889634f * z));
}
__device__ inline float fast_tanh(float z) {
  return 1.0f - 2.0f / (1.0f + exp2f(2.8853900817779268f * z));
}

#define SB0() __builtin_amdgcn_sched_barrier(0)

// ---------------- fused convert: x,h -> fp8; all 6 weights -> fp8(x2^13) ----------------
struct ConvArgs3 {
  const float* x; const float* h;
  const float* w[6];                 // W_r, U_r, W_u, U_u, W_c, U_c
  u8* x8; u8* h8;
  u8* w8[6];
};

__global__ __launch_bounds__(256) void convert_all(ConvArgs3 a) {
  const int b = blockIdx.x;
  const int t = threadIdx.x;
  if (b < 16384) {
    const bool isx = b < 8192;
    const int off = isx ? b : b - 8192;
    const float* __restrict__ s = isx ? a.x : a.h;
    u8* __restrict__ d8 = isx ? a.x8 : a.h8;
    const int i = (off * 256 + t) * 4;
    float4 v = *(const float4*)(s + i);
    unsigned q = f2fp8(v.x) | (f2fp8(v.y) << 8) | (f2fp8(v.z) << 16) | (f2fp8(v.w) << 24);
    *(unsigned*)(d8 + i) = q;
  } else {
    const int tt = b - 16384;
    const int which = tt >> 10;      // 0..5
    const int off = tt & 1023;
    const float* __restrict__ s = a.w[which];
    u8* __restrict__ d8 = a.w8[which];
    const int i = (off * 256 + t) * 4;
    float4 v = *(const float4*)(s + i);
    unsigned q = f2fp8(v.x * 8192.f) | (f2fp8(v.y * 8192.f) << 8) |
                 (f2fp8(v.z * 8192.f) << 16) | (f2fp8(v.w * 8192.f) << 24);
    *(unsigned*)(d8 + i) = q;
  }
}

// ---------------- fp8 MX GEMM: Y(fp8) = A @ W^T, 128x128 tile, BK=128, dbuf, 2 blocks/CU ----------------
// 256 thr = 4 waves (2M x 2N), per-wave 64x64 out. LDS 64 KiB -> 2 blocks/CU.
// XOR swizzle phys kgroup = logical ^ (row&7); counted vmcnt(8), never 0 mid-loop.
// Scales: A = 2^0 (127), W x2^13 -> 2^-13 (114). Output stored as fp8 e4m3 (|z| <~ 6).
struct GemmF8 { const u8* A[4]; const u8* Bw[4]; u8* Y[4]; };

template <int NG>
__global__ __launch_bounds__(256, 2) void gemm_f8s(GemmF8 args) {
  const int p = blockIdx.x;                        // NG*512 blocks
  const int wg = (p & 7) * (NG * 64) + (p >> 3);   // XCD-contiguous, bijective (grid % 8 == 0)
  const int gate = wg >> 9;                        // 0..NG-1
  const int rem  = wg & 511;
  const int rblk = rem >> 3;                       // 0..63 (128-row panel)
  const int cblk = rem & 7;                        // 0..7  (128-col panel; fastest -> A-panel L2 reuse)

  const u8* __restrict__ A  = args.A[gate];
  const u8* __restrict__ Bw = args.Bw[gate];
  u8* __restrict__ Y = args.Y[gate];

  __shared__ __attribute__((aligned(16))) u8 smA[2][128 * 128];  // 32 KiB
  __shared__ __attribute__((aligned(16))) u8 smB[2][128 * 128];  // 32 KiB

  const int tid  = threadIdx.x;
  const int lane = tid & 63;
  const int w    = tid >> 6;     // 0..3
  const int wm   = w >> 1;       // 0..1 (M half)
  const int wn   = w & 1;        // 0..1 (N half)

  const int l8   = lane >> 3;                 // row within 8-row group
  const int sgrp = (lane & 7) ^ l8;           // pre-swizzled logical col-group (16B units)
  const u8* aSrc = A  + ((size_t)(rblk * 128 + w * 32 + l8) << 10) + sgrp * 16;
  const u8* bSrc = Bw + ((size_t)(cblk * 128 + w * 32 + l8) << 10) + sgrp * 16;

  const int sw = lane & 7;
  const int g0 = (lane >> 4) * 2;
  const int o0 = ((g0 ^ sw) << 4);
  const int o1 = (((g0 + 1) ^ sw) << 4);
  const int frA = (wm * 64 + (lane & 15)) * 128;
  const int frB = (wn * 64 + (lane & 15)) * 128;

  f32x4 acc[4][4] = {};   // m 0..3 x n 0..3 (16x16 blocks of the 64x64 output)

  auto stage = [&](int tt) {
    const int cur = tt & 1;
    const size_t ko = (size_t)tt * 128;
#pragma unroll
    for (int i = 0; i < 4; ++i) {
      async16(aSrc + (size_t)i * 8192 + ko, &smA[cur][(w * 32 + i * 8) * 128]);
      async16(bSrc + (size_t)i * 8192 + ko, &smB[cur][(w * 32 + i * 8) * 128]);
    }
  };

  // prologue: tiles 0 and 1 (8 loads/thread each)
  stage(0);
  stage(1);
  asm volatile("s_waitcnt vmcnt(8)" ::: "memory");   // tile 0 landed (tile 1 may fly)
  __builtin_amdgcn_s_barrier();

  for (int t = 0; t < 8; ++t) {
    const int cur = t & 1;
    const u8* bA = &smA[cur][0];
    const u8* bB = &smB[cur][0];

    i32x8 af[4], bf[4];
#pragma unroll
    for (int m = 0; m < 4; ++m) {
      const int ra = frA + m * 2048;
      af[m] = join8(*(const i32x4*)&bA[ra + o0], *(const i32x4*)&bA[ra + o1]);
    }
#pragma unroll
    for (int n = 0; n < 4; ++n) {
      const int rb = frB + n * 2048;
      bf[n] = join8(*(const i32x4*)&bB[rb + o0], *(const i32x4*)&bB[rb + o1]);
    }
    asm volatile("s_waitcnt lgkmcnt(0)" ::: "memory");
    SB0();
    __builtin_amdgcn_s_barrier();          // all waves done reading buf[cur]

    if (t + 2 < 8) stage(t + 2);           // overwrite buf[cur] with tile t+2
    SB0();
    __builtin_amdgcn_s_setprio(1);
#pragma unroll
    for (int m = 0; m < 4; ++m)
#pragma unroll
      for (int n = 0; n < 4; ++n)
        acc[m][n] = __builtin_amdgcn_mfma_scale_f32_16x16x128_f8f6f4(
            af[m], bf[n], acc[m][n], 0, 0, 0, 127, 0, 114);
    __builtin_amdgcn_s_setprio(0);
    SB0();
    if (t < 6)       asm volatile("s_waitcnt vmcnt(8)" ::: "memory");
    else if (t == 6) asm volatile("s_waitcnt vmcnt(0)" ::: "memory");  // drain tile 7
    SB0();
    __builtin_amdgcn_s_barrier();
  }

  // epilogue (fp8 out): C/D layout col=lane&15, row=(lane>>4)*4+reg
  const int rBase = rblk * 128 + wm * 64 + (lane >> 4) * 4;
  const int cBase = cblk * 128 + wn * 64 + (lane & 15);
#pragma unroll
  for (int m = 0; m < 4; ++m) {
#pragma unroll
    for (int i = 0; i < 4; ++i) {
      const size_t r0 = (size_t)(rBase + m * 16 + i) * 1024 + cBase;
#pragma unroll
      for (int n = 0; n < 4; ++n)
        Y[r0 + n * 16] = (u8)f2fp8(acc[m][n][i]);
    }
  }
}

// ---------------- r gate: wave-per-row; Y inputs fp8; reads h fp32; writes hr as fp8 ----------------
__global__ __launch_bounds__(256) void rgate_kernel(
    const u8* __restrict__ Yrh, const u8* __restrict__ Yrx,
    const float* __restrict__ h, const float* __restrict__ gamma,
    const float* __restrict__ beta, u8* __restrict__ hr8) {
  const int row  = blockIdx.x * 4 + (threadIdx.x >> 6);
  const int lane = threadIdx.x & 63;
  const size_t rb = (size_t)row * 1024;

  uint2 qa[2], qb[2];
  float4 hf[4];
#pragma unroll
  for (int c = 0; c < 2; c++) {
    const int cb = c * 512 + lane * 8;
    qa[c] = *(const uint2*)(Yrh + rb + cb);
    qb[c] = *(const uint2*)(Yrx + rb + cb);
    hf[c * 2]     = *(const float4*)(h + rb + cb);
    hf[c * 2 + 1] = *(const float4*)(h + rb + cb + 4);
  }

  float va[16], vb[16];
  unpack8f8(qa[0], va); unpack8f8(qa[1], va + 8);
  unpack8f8(qb[0], vb); unpack8f8(qb[1], vb + 8);

  float s0 = 0.f, s0q = 0.f, s1 = 0.f, s1q = 0.f;
#pragma unroll
  for (int j = 0; j < 16; j++) {
    s0 += va[j]; s0q += va[j] * va[j];
    s1 += vb[j]; s1q += vb[j] * vb[j];
  }
#pragma unroll
  for (int off = 1; off < 64; off <<= 1) {
    s0 += __shfl_xor(s0, off, 64);  s0q += __shfl_xor(s0q, off, 64);
    s1 += __shfl_xor(s1, off, 64);  s1q += __shfl_xor(s1q, off, 64);
  }

  const float inv = 1.0f / 1024.0f;
  const float mu0 = s0 * inv, rs0 = rsqrtf(s0q * inv - mu0 * mu0 + 1e-5f);
  const float mu1 = s1 * inv, rs1 = rsqrtf(s1q * inv - mu1 * mu1 + 1e-5f);

#pragma unroll
  for (int c = 0; c < 2; c++) {
    const int cb = c * 512 + lane * 8;
    const float* hv = (const float*)&hf[c * 2];
    float o[8];
#pragma unroll
    for (int j = 0; j < 8; j++) {
      const int jj = c * 8 + j;
      const float ln0 = (va[jj] - mu0) * rs0 * gamma[cb + j] + beta[cb + j];
      const float ln1 = (vb[jj] - mu1) * rs1 * gamma[1024 + cb + j] + beta[1024 + cb + j];
      const float rg = fast_sigmoid(ln0 + ln1);
      o[j] = hv[j] * rg;
    }
    uint2 q;
    q.x = f2fp8(o[0]) | (f2fp8(o[1]) << 8) | (f2fp8(o[2]) << 16) | (f2fp8(o[3]) << 24);
    q.y = f2fp8(o[4]) | (f2fp8(o[5]) << 8) | (f2fp8(o[6]) << 16) | (f2fp8(o[7]) << 24);
    *(uint2*)(hr8 + rb + cb) = q;
  }
}

// ---------------- final: wave-per-row; Y inputs fp8; h read in fp32 ----------------
__global__ __launch_bounds__(256) void final_fuse(
    const u8* __restrict__ Yuh, const u8* __restrict__ Yux,
    const u8* __restrict__ Ych, const u8* __restrict__ Ycx,
    const float* __restrict__ h, const float* __restrict__ gamma,
    const float* __restrict__ beta, float* __restrict__ out) {
  const int row  = blockIdx.x * 4 + (threadIdx.x >> 6);
  const int lane = threadIdx.x & 63;
  const size_t rb = (size_t)row * 1024;

  uint2 q0[2], q1[2], q2[2], q3[2];
  float4 hf[4];
#pragma unroll
  for (int c = 0; c < 2; c++) {
    const int cb = c * 512 + lane * 8;
    q0[c] = *(const uint2*)(Yuh + rb + cb);
    q1[c] = *(const uint2*)(Yux + rb + cb);
    q2[c] = *(const uint2*)(Ych + rb + cb);
    q3[c] = *(const uint2*)(Ycx + rb + cb);
    hf[c * 2]     = *(const float4*)(h + rb + cb);
    hf[c * 2 + 1] = *(const float4*)(h + rb + cb + 4);
  }

  float s[8] = {0.f, 0.f, 0.f, 0.f, 0.f, 0.f, 0.f, 0.f};
  float tmp[8];
#pragma unroll
  for (int c = 0; c < 2; c++) {
    unpack8f8(q0[c], tmp);
#pragma unroll
    for (int j = 0; j < 8; j++) { s[0] += tmp[j]; s[1] += tmp[j] * tmp[j]; }
    unpack8f8(q1[c], tmp);
#pragma unroll
    for (int j = 0; j < 8; j++) { s[2] += tmp[j]; s[3] += tmp[j] * tmp[j]; }
    unpack8f8(q2[c], tmp);
#pragma unroll
    for (int j = 0; j < 8; j++) { s[4] += tmp[j]; s[5] += tmp[j] * tmp[j]; }
    unpack8f8(q3[c], tmp);
#pragma unroll
    for (int j = 0; j < 8; j++) { s[6] += tmp[j]; s[7] += tmp[j] * tmp[j]; }
  }
#pragma unroll
  for (int off = 1; off < 64; off <<= 1) {
#pragma unroll
    for (int q = 0; q < 8; q++) s[q] += __shfl_xor(s[q], off, 64);
  }

  const float inv = 1.0f / 1024.0f;
  const float mu0 = s[0] * inv, rs0 = rsqrtf(s[1] * inv - mu0 * mu0 + 1e-5f);
  const float mu1 = s[2] * inv, rs1 = rsqrtf(s[3] * inv - mu1 * mu1 + 1e-5f);
  const float mu2 = s[4] * inv, rs2 = rsqrtf(s[5] * inv - mu2 * mu2 + 1e-5f);
  const float mu3 = s[6] * inv, rs3 = rsqrtf(s[7] * inv - mu3 * mu3 + 1e-5f);

#pragma unroll
  for (int c = 0; c < 2; c++) {
    const int cb = c * 512 + lane * 8;
    float v0[8], v1[8], v2[8], v3[8];
    unpack8f8(q0[c], v0); unpack8f8(q1[c], v1); unpack8f8(q2[c], v2); unpack8f8(q3[c], v3);
    const float* hv = (const float*)&hf[c * 2];
    float o[8];
#pragma unroll
    for (int j = 0; j < 8; j++) {
      const int cc = cb + j;
      const float ln2 = (v0[j] - mu0) * rs0 * gamma[2 * 1024 + cc] + beta[2 * 1024 + cc];
      const float ln3 = (v1[j] - mu1) * rs1 * gamma[3 * 1024 + cc] + beta[3 * 1024 + cc];
      const float ln4 = (v2[j] - mu2) * rs2 * gamma[4 * 1024 + cc] + beta[4 * 1024 + cc];
      const float ln5 = (v3[j] - mu3) * rs3 * gamma[5 * 1024 + cc] + beta[5 * 1024 + cc];
      const float u  = fast_sigmoid(ln2 + ln3);
      const float cg = fast_tanh(ln4 + ln5);
      o[j] = (1.0f - u) * hv[j] + u * cg;
    }
    *(float4*)(out + rb + cb)     = *(float4*)&o[0];
    *(float4*)(out + rb + cb + 4) = *(float4*)&o[4];
  }
}

extern "C" void kernel_launch(void* const* d_in, const int* in_sizes, int n_in,
                              void* d_out, int out_size, void* d_ws, size_t ws_size,
                              hipStream_t stream) {
  const float* x  = (const float*)d_in[0];
  const float* h  = (const float*)d_in[1];
  const float* W_r = (const float*)d_in[2];
  const float* U_r = (const float*)d_in[3];
  const float* W_u = (const float*)d_in[4];
  const float* U_u = (const float*)d_in[5];
  const float* W_c = (const float*)d_in[6];
  const float* U_c = (const float*)d_in[7];
  const float* gamma = (const float*)d_in[8];
  const float* beta  = (const float*)d_in[9];
  float* out = (float*)d_out;

  char* ws = (char*)d_ws;
  const size_t MB = 1024 * 1024;

  u8* x8  = (u8*)(ws);                        // 8 MiB
  u8* h8  = (u8*)(ws + 8 * MB);               // 8 MiB
  u8* hr8 = (u8*)(ws + 16 * MB);              // 8 MiB
  u8* w8[6];
  for (int i = 0; i < 6; i++) w8[i] = (u8*)(ws + 24 * MB + i * MB);  // 6 MiB
  u8* Y0 = (u8*)(ws + 32 * MB);               // r_hidden -> c_hidden (reused), fp8
  u8* Y1 = (u8*)(ws + 40 * MB);               // r_input (dead after rgate), fp8
  u8* Y2 = (u8*)(ws + 48 * MB);               // u_hidden, fp8
  u8* Y3 = (u8*)(ws + 56 * MB);               // u_input, fp8
  u8* Y5 = (u8*)(ws + 64 * MB);               // c_input, fp8
  // total ws: 72 MiB

  // 1) fused convert: x,h -> fp8; 6 weights -> fp8 x2^13
  ConvArgs3 ca = {};
  ca.x = x; ca.h = h;
  ca.w[0] = W_r; ca.w[1] = U_r; ca.w[2] = W_u; ca.w[3] = U_u; ca.w[4] = W_c; ca.w[5] = U_c;
  ca.x8 = x8; ca.h8 = h8;
  for (int i = 0; i < 6; i++) ca.w8[i] = w8[i];
  convert_all<<<22528, 256, 0, stream>>>(ca);

  // 2) fp8 GEMMs, pre-rgate gates: r_h, r_x, u_x, c_x  (2048 blocks x 256 thr, 2 blocks/CU)
  GemmF8 gA = {};
  gA.A[0] = h8; gA.Bw[0] = w8[0]; gA.Y[0] = Y0;   // r_h = h@W_r^T
  gA.A[1] = x8; gA.Bw[1] = w8[1]; gA.Y[1] = Y1;   // r_x = x@U_r^T
  gA.A[2] = x8; gA.Bw[2] = w8[3]; gA.Y[2] = Y3;   // u_x = x@U_u^T
  gA.A[3] = x8; gA.Bw[3] = w8[5]; gA.Y[3] = Y5;   // c_x = x@U_c^T
  gemm_f8s<4><<<2048, 256, 0, stream>>>(gA);

  // 3) r gate: hr = h * sigmoid(LN(r_h)+LN(r_x)), written as fp8
  rgate_kernel<<<2048, 256, 0, stream>>>(Y0, Y1, h, gamma, beta, hr8);

  // 4) fp8 GEMMs, post-rgate gates: u_h, c_h  (1024 blocks)
  GemmF8 gB = {};
  gB.A[0] = h8;  gB.Bw[0] = w8[2]; gB.Y[0] = Y2;  // u_h = h@W_u^T
  gB.A[1] = hr8; gB.Bw[1] = w8[4]; gB.Y[1] = Y0;  // c_h = hr@W_c^T (Y0 reuse)
  gemm_f8s<2><<<1024, 256, 0, stream>>>(gB);

  // 5) u, c, out (h in fp32)
  final_fuse<<<2048, 256, 0, stream>>>(Y2, Y3, Y0, Y5, h, gamma, beta, out);
}

// Round 9
// 632.081 us; speedup vs baseline: 1.1038x; 1.1038x over previous
//
#include <hip/hip_runtime.h>
#include <cstdint>
#include <cstddef>

typedef unsigned short u16;
typedef unsigned char u8;
typedef __attribute__((ext_vector_type(4))) float f32x4;
typedef __attribute__((ext_vector_type(4))) int i32x4;
typedef __attribute__((ext_vector_type(8))) int i32x8;

__device__ inline float bf2f(u16 u) { return __uint_as_float(((unsigned)u) << 16); }
__device__ inline unsigned f2bf(float f) {
  unsigned u = __float_as_uint(f);
  u += 0x7fffu + ((u >> 16) & 1u);   // RNE
  return u >> 16;
}

// f32 -> OCP e4m3fn (RNE). Caller guarantees |f| <= 448.
__device__ inline unsigned f2fp8(float f) {
  unsigned s = (__float_as_uint(f) >> 31) << 7;
  float a = fabsf(f);
  if (a >= 0.015625f) {              // normal range
    unsigned u = __float_as_uint(a);
    u += 0x7FFFFu + ((u >> 20) & 1u);
    unsigned e = (u >> 23) - 120u;   // e32 - 127 + 7
    unsigned m = (u >> 20) & 7u;
    return s | (e << 3) | m;
  }
  int m = (int)rintf(a * 512.0f);    // subnormal step 2^-9 (m=8 rolls to min normal)
  return s | (unsigned)m;
}

// OCP e4m3fn -> f32 (branchless-ish decode; subnormal step 2^-9)
__device__ inline float fp82f(unsigned b) {
  unsigned em = b & 0x7fu;
  float v = (em >= 8u)
      ? __uint_as_float((((em >> 3) + 120u) << 23) | ((em & 7u) << 20))
      : (float)em * 0.001953125f;
  return (b & 0x80u) ? -v : v;
}

__device__ inline void unpack8f8(uint2 q, float* o) {
  o[0] = fp82f(q.x & 255u);  o[1] = fp82f((q.x >> 8) & 255u);
  o[2] = fp82f((q.x >> 16) & 255u);  o[3] = fp82f(q.x >> 24);
  o[4] = fp82f(q.y & 255u);  o[5] = fp82f((q.y >> 8) & 255u);
  o[6] = fp82f((q.y >> 16) & 255u);  o[7] = fp82f(q.y >> 24);
}

__device__ inline void async16(const void* g, void* l) {
  __builtin_amdgcn_global_load_lds(
      (const __attribute__((address_space(1))) void*)g,
      (__attribute__((address_space(3))) void*)l, 16, 0, 0);
}

__device__ inline i32x8 join8(i32x4 lo, i32x4 hi) {
  i32x8 r;
  r[0] = lo[0]; r[1] = lo[1]; r[2] = lo[2]; r[3] = lo[3];
  r[4] = hi[0]; r[5] = hi[1]; r[6] = hi[2]; r[7] = hi[3];
  return r;
}

__device__ inline float fast_sigmoid(float z) {
  return 1.0f / (1.0f + exp2f(-1.4426950408889634f * z));
}
__device__ inline float fast_tanh(float z) {
  return 1.0f - 2.0f / (1.0f + exp2f(2.8853900817779268f * z));
}

#define SB0() __builtin_amdgcn_sched_barrier(0)

// ---------------- fused convert: x,h -> fp8; all 6 weights -> fp8(x2^13) ----------------
struct ConvArgs3 {
  const float* x; const float* h;
  const float* w[6];                 // W_r, U_r, W_u, U_u, W_c, U_c
  u8* x8; u8* h8;
  u8* w8[6];
};

__global__ __launch_bounds__(256) void convert_all(ConvArgs3 a) {
  const int b = blockIdx.x;
  const int t = threadIdx.x;
  if (b < 16384) {
    const bool isx = b < 8192;
    const int off = isx ? b : b - 8192;
    const float* __restrict__ s = isx ? a.x : a.h;
    u8* __restrict__ d8 = isx ? a.x8 : a.h8;
    const int i = (off * 256 + t) * 4;
    float4 v = *(const float4*)(s + i);
    unsigned q = f2fp8(v.x) | (f2fp8(v.y) << 8) | (f2fp8(v.z) << 16) | (f2fp8(v.w) << 24);
    *(unsigned*)(d8 + i) = q;
  } else {
    const int tt = b - 16384;
    const int which = tt >> 10;      // 0..5
    const int off = tt & 1023;
    const float* __restrict__ s = a.w[which];
    u8* __restrict__ d8 = a.w8[which];
    const int i = (off * 256 + t) * 4;
    float4 v = *(const float4*)(s + i);
    unsigned q = f2fp8(v.x * 8192.f) | (f2fp8(v.y * 8192.f) << 8) |
                 (f2fp8(v.z * 8192.f) << 16) | (f2fp8(v.w * 8192.f) << 24);
    *(unsigned*)(d8 + i) = q;
  }
}

// ---------------- fp8 MX GEMM: Y(fp8) = A @ W^T, 128x128 tile, BK=128, dbuf, 2 blocks/CU ----------------
// 256 thr = 4 waves (2M x 2N), per-wave 64x64 out. LDS 64 KiB -> 2 blocks/CU.
// XOR swizzle phys kgroup = logical ^ (row&7); counted vmcnt(8), never 0 mid-loop.
// Scales: A = 2^0 (127), W x2^13 -> 2^-13 (114).
// Epilogue: fragments -> LDS scratch -> coalesced 16B stores. R7 lesson: direct byte-scatter
// stores (16B fragments per 1KiB row) caused L2 sector RMW -> FETCH 22->700 MB, 45->347 us.
struct GemmF8 { const u8* A[4]; const u8* Bw[4]; u8* Y[4]; };

template <int NG>
__global__ __launch_bounds__(256, 2) void gemm_f8s(GemmF8 args) {
  const int p = blockIdx.x;                        // NG*512 blocks
  const int wg = (p & 7) * (NG * 64) + (p >> 3);   // XCD-contiguous, bijective (grid % 8 == 0)
  const int gate = wg >> 9;                        // 0..NG-1
  const int rem  = wg & 511;
  const int rblk = rem >> 3;                       // 0..63 (128-row panel)
  const int cblk = rem & 7;                        // 0..7  (128-col panel; fastest -> A-panel L2 reuse)

  const u8* __restrict__ A  = args.A[gate];
  const u8* __restrict__ Bw = args.Bw[gate];
  u8* __restrict__ Y = args.Y[gate];

  __shared__ __attribute__((aligned(16))) u8 smA[2][128 * 128];  // 32 KiB
  __shared__ __attribute__((aligned(16))) u8 smB[2][128 * 128];  // 32 KiB

  const int tid  = threadIdx.x;
  const int lane = tid & 63;
  const int w    = tid >> 6;     // 0..3
  const int wm   = w >> 1;       // 0..1 (M half)
  const int wn   = w & 1;        // 0..1 (N half)

  const int l8   = lane >> 3;                 // row within 8-row group
  const int sgrp = (lane & 7) ^ l8;           // pre-swizzled logical col-group (16B units)
  const u8* aSrc = A  + ((size_t)(rblk * 128 + w * 32 + l8) << 10) + sgrp * 16;
  const u8* bSrc = Bw + ((size_t)(cblk * 128 + w * 32 + l8) << 10) + sgrp * 16;

  const int sw = lane & 7;
  const int g0 = (lane >> 4) * 2;
  const int o0 = ((g0 ^ sw) << 4);
  const int o1 = (((g0 + 1) ^ sw) << 4);
  const int frA = (wm * 64 + (lane & 15)) * 128;
  const int frB = (wn * 64 + (lane & 15)) * 128;

  f32x4 acc[4][4] = {};   // m 0..3 x n 0..3 (16x16 blocks of the 64x64 output)

  auto stage = [&](int tt) {
    const int cur = tt & 1;
    const size_t ko = (size_t)tt * 128;
#pragma unroll
    for (int i = 0; i < 4; ++i) {
      async16(aSrc + (size_t)i * 8192 + ko, &smA[cur][(w * 32 + i * 8) * 128]);
      async16(bSrc + (size_t)i * 8192 + ko, &smB[cur][(w * 32 + i * 8) * 128]);
    }
  };

  // prologue: tiles 0 and 1 (8 loads/thread each)
  stage(0);
  stage(1);
  asm volatile("s_waitcnt vmcnt(8)" ::: "memory");   // tile 0 landed (tile 1 may fly)
  __builtin_amdgcn_s_barrier();

  for (int t = 0; t < 8; ++t) {
    const int cur = t & 1;
    const u8* bA = &smA[cur][0];
    const u8* bB = &smB[cur][0];

    i32x8 af[4], bf[4];
#pragma unroll
    for (int m = 0; m < 4; ++m) {
      const int ra = frA + m * 2048;
      af[m] = join8(*(const i32x4*)&bA[ra + o0], *(const i32x4*)&bA[ra + o1]);
    }
#pragma unroll
    for (int n = 0; n < 4; ++n) {
      const int rb = frB + n * 2048;
      bf[n] = join8(*(const i32x4*)&bB[rb + o0], *(const i32x4*)&bB[rb + o1]);
    }
    asm volatile("s_waitcnt lgkmcnt(0)" ::: "memory");
    SB0();
    __builtin_amdgcn_s_barrier();          // all waves done reading buf[cur]

    if (t + 2 < 8) stage(t + 2);           // overwrite buf[cur] with tile t+2
    SB0();
    __builtin_amdgcn_s_setprio(1);
#pragma unroll
    for (int m = 0; m < 4; ++m)
#pragma unroll
      for (int n = 0; n < 4; ++n)
        acc[m][n] = __builtin_amdgcn_mfma_scale_f32_16x16x128_f8f6f4(
            af[m], bf[n], acc[m][n], 0, 0, 0, 127, 0, 114);
    __builtin_amdgcn_s_setprio(0);
    SB0();
    if (t < 6)       asm volatile("s_waitcnt vmcnt(8)" ::: "memory");
    else if (t == 6) asm volatile("s_waitcnt vmcnt(0)" ::: "memory");  // drain tile 7
    SB0();
    __builtin_amdgcn_s_barrier();
  }

  // epilogue: fp8 fragments -> LDS [128][128] scratch -> coalesced 16B full-sector stores.
  // smA is dead (last LDS read drained >=2 barriers ago); 16 KiB scratch fits in smA.
  u8* scratch = (u8*)&smA[0][0];
#pragma unroll
  for (int m = 0; m < 4; ++m) {
#pragma unroll
    for (int i = 0; i < 4; ++i) {
      const int row = wm * 64 + m * 16 + (lane >> 4) * 4 + i;
#pragma unroll
      for (int n = 0; n < 4; ++n)
        scratch[row * 128 + wn * 64 + (lane & 15) + n * 16] = (u8)f2fp8(acc[m][n][i]);
    }
  }
  __syncthreads();
  const int orow = tid >> 1, ohalf = tid & 1;
  const u8* srcp = scratch + orow * 128 + ohalf * 64;
  u8* dstp = Y + (size_t)(rblk * 128 + orow) * 1024 + cblk * 128 + ohalf * 64;
#pragma unroll
  for (int k = 0; k < 4; ++k)
    *(uint4*)(dstp + k * 16) = *(const uint4*)(srcp + k * 16);
}

// ---------------- r gate: wave-per-row; Y inputs fp8; reads h fp32; writes hr as fp8 ----------------
__global__ __launch_bounds__(256) void rgate_kernel(
    const u8* __restrict__ Yrh, const u8* __restrict__ Yrx,
    const float* __restrict__ h, const float* __restrict__ gamma,
    const float* __restrict__ beta, u8* __restrict__ hr8) {
  const int row  = blockIdx.x * 4 + (threadIdx.x >> 6);
  const int lane = threadIdx.x & 63;
  const size_t rb = (size_t)row * 1024;

  uint2 qa[2], qb[2];
  float4 hf[4];
#pragma unroll
  for (int c = 0; c < 2; c++) {
    const int cb = c * 512 + lane * 8;
    qa[c] = *(const uint2*)(Yrh + rb + cb);
    qb[c] = *(const uint2*)(Yrx + rb + cb);
    hf[c * 2]     = *(const float4*)(h + rb + cb);
    hf[c * 2 + 1] = *(const float4*)(h + rb + cb + 4);
  }

  float va[16], vb[16];
  unpack8f8(qa[0], va); unpack8f8(qa[1], va + 8);
  unpack8f8(qb[0], vb); unpack8f8(qb[1], vb + 8);

  float s0 = 0.f, s0q = 0.f, s1 = 0.f, s1q = 0.f;
#pragma unroll
  for (int j = 0; j < 16; j++) {
    s0 += va[j]; s0q += va[j] * va[j];
    s1 += vb[j]; s1q += vb[j] * vb[j];
  }
#pragma unroll
  for (int off = 1; off < 64; off <<= 1) {
    s0 += __shfl_xor(s0, off, 64);  s0q += __shfl_xor(s0q, off, 64);
    s1 += __shfl_xor(s1, off, 64);  s1q += __shfl_xor(s1q, off, 64);
  }

  const float inv = 1.0f / 1024.0f;
  const float mu0 = s0 * inv, rs0 = rsqrtf(s0q * inv - mu0 * mu0 + 1e-5f);
  const float mu1 = s1 * inv, rs1 = rsqrtf(s1q * inv - mu1 * mu1 + 1e-5f);

#pragma unroll
  for (int c = 0; c < 2; c++) {
    const int cb = c * 512 + lane * 8;
    const float* hv = (const float*)&hf[c * 2];
    float o[8];
#pragma unroll
    for (int j = 0; j < 8; j++) {
      const int jj = c * 8 + j;
      const float ln0 = (va[jj] - mu0) * rs0 * gamma[cb + j] + beta[cb + j];
      const float ln1 = (vb[jj] - mu1) * rs1 * gamma[1024 + cb + j] + beta[1024 + cb + j];
      const float rg = fast_sigmoid(ln0 + ln1);
      o[j] = hv[j] * rg;
    }
    uint2 q;
    q.x = f2fp8(o[0]) | (f2fp8(o[1]) << 8) | (f2fp8(o[2]) << 16) | (f2fp8(o[3]) << 24);
    q.y = f2fp8(o[4]) | (f2fp8(o[5]) << 8) | (f2fp8(o[6]) << 16) | (f2fp8(o[7]) << 24);
    *(uint2*)(hr8 + rb + cb) = q;
  }
}

// ---------------- final: wave-per-row; Y inputs fp8; h read in fp32 ----------------
__global__ __launch_bounds__(256) void final_fuse(
    const u8* __restrict__ Yuh, const u8* __restrict__ Yux,
    const u8* __restrict__ Ych, const u8* __restrict__ Ycx,
    const float* __restrict__ h, const float* __restrict__ gamma,
    const float* __restrict__ beta, float* __restrict__ out) {
  const int row  = blockIdx.x * 4 + (threadIdx.x >> 6);
  const int lane = threadIdx.x & 63;
  const size_t rb = (size_t)row * 1024;

  uint2 q0[2], q1[2], q2[2], q3[2];
  float4 hf[4];
#pragma unroll
  for (int c = 0; c < 2; c++) {
    const int cb = c * 512 + lane * 8;
    q0[c] = *(const uint2*)(Yuh + rb + cb);
    q1[c] = *(const uint2*)(Yux + rb + cb);
    q2[c] = *(const uint2*)(Ych + rb + cb);
    q3[c] = *(const uint2*)(Ycx + rb + cb);
    hf[c * 2]     = *(const float4*)(h + rb + cb);
    hf[c * 2 + 1] = *(const float4*)(h + rb + cb + 4);
  }

  float s[8] = {0.f, 0.f, 0.f, 0.f, 0.f, 0.f, 0.f, 0.f};
  float tmp[8];
#pragma unroll
  for (int c = 0; c < 2; c++) {
    unpack8f8(q0[c], tmp);
#pragma unroll
    for (int j = 0; j < 8; j++) { s[0] += tmp[j]; s[1] += tmp[j] * tmp[j]; }
    unpack8f8(q1[c], tmp);
#pragma unroll
    for (int j = 0; j < 8; j++) { s[2] += tmp[j]; s[3] += tmp[j] * tmp[j]; }
    unpack8f8(q2[c], tmp);
#pragma unroll
    for (int j = 0; j < 8; j++) { s[4] += tmp[j]; s[5] += tmp[j] * tmp[j]; }
    unpack8f8(q3[c], tmp);
#pragma unroll
    for (int j = 0; j < 8; j++) { s[6] += tmp[j]; s[7] += tmp[j] * tmp[j]; }
  }
#pragma unroll
  for (int off = 1; off < 64; off <<= 1) {
#pragma unroll
    for (int q = 0; q < 8; q++) s[q] += __shfl_xor(s[q], off, 64);
  }

  const float inv = 1.0f / 1024.0f;
  const float mu0 = s[0] * inv, rs0 = rsqrtf(s[1] * inv - mu0 * mu0 + 1e-5f);
  const float mu1 = s[2] * inv, rs1 = rsqrtf(s[3] * inv - mu1 * mu1 + 1e-5f);
  const float mu2 = s[4] * inv, rs2 = rsqrtf(s[5] * inv - mu2 * mu2 + 1e-5f);
  const float mu3 = s[6] * inv, rs3 = rsqrtf(s[7] * inv - mu3 * mu3 + 1e-5f);

#pragma unroll
  for (int c = 0; c < 2; c++) {
    const int cb = c * 512 + lane * 8;
    float v0[8], v1[8], v2[8], v3[8];
    unpack8f8(q0[c], v0); unpack8f8(q1[c], v1); unpack8f8(q2[c], v2); unpack8f8(q3[c], v3);
    const float* hv = (const float*)&hf[c * 2];
    float o[8];
#pragma unroll
    for (int j = 0; j < 8; j++) {
      const int cc = cb + j;
      const float ln2 = (v0[j] - mu0) * rs0 * gamma[2 * 1024 + cc] + beta[2 * 1024 + cc];
      const float ln3 = (v1[j] - mu1) * rs1 * gamma[3 * 1024 + cc] + beta[3 * 1024 + cc];
      const float ln4 = (v2[j] - mu2) * rs2 * gamma[4 * 1024 + cc] + beta[4 * 1024 + cc];
      const float ln5 = (v3[j] - mu3) * rs3 * gamma[5 * 1024 + cc] + beta[5 * 1024 + cc];
      const float u  = fast_sigmoid(ln2 + ln3);
      const float cg = fast_tanh(ln4 + ln5);
      o[j] = (1.0f - u) * hv[j] + u * cg;
    }
    *(float4*)(out + rb + cb)     = *(float4*)&o[0];
    *(float4*)(out + rb + cb + 4) = *(float4*)&o[4];
  }
}

extern "C" void kernel_launch(void* const* d_in, const int* in_sizes, int n_in,
                              void* d_out, int out_size, void* d_ws, size_t ws_size,
                              hipStream_t stream) {
  const float* x  = (const float*)d_in[0];
  const float* h  = (const float*)d_in[1];
  const float* W_r = (const float*)d_in[2];
  const float* U_r = (const float*)d_in[3];
  const float* W_u = (const float*)d_in[4];
  const float* U_u = (const float*)d_in[5];
  const float* W_c = (const float*)d_in[6];
  const float* U_c = (const float*)d_in[7];
  const float* gamma = (const float*)d_in[8];
  const float* beta  = (const float*)d_in[9];
  float* out = (float*)d_out;

  char* ws = (char*)d_ws;
  const size_t MB = 1024 * 1024;

  u8* x8  = (u8*)(ws);                        // 8 MiB
  u8* h8  = (u8*)(ws + 8 * MB);               // 8 MiB
  u8* hr8 = (u8*)(ws + 16 * MB);              // 8 MiB
  u8* w8[6];
  for (int i = 0; i < 6; i++) w8[i] = (u8*)(ws + 24 * MB + i * MB);  // 6 MiB
  u8* Y0 = (u8*)(ws + 32 * MB);               // r_hidden -> c_hidden (reused), fp8
  u8* Y1 = (u8*)(ws + 40 * MB);               // r_input (dead after rgate), fp8
  u8* Y2 = (u8*)(ws + 48 * MB);               // u_hidden, fp8
  u8* Y3 = (u8*)(ws + 56 * MB);               // u_input, fp8
  u8* Y5 = (u8*)(ws + 64 * MB);               // c_input, fp8
  // total ws: 72 MiB

  // 1) fused convert: x,h -> fp8; 6 weights -> fp8 x2^13
  ConvArgs3 ca = {};
  ca.x = x; ca.h = h;
  ca.w[0] = W_r; ca.w[1] = U_r; ca.w[2] = W_u; ca.w[3] = U_u; ca.w[4] = W_c; ca.w[5] = U_c;
  ca.x8 = x8; ca.h8 = h8;
  for (int i = 0; i < 6; i++) ca.w8[i] = w8[i];
  convert_all<<<22528, 256, 0, stream>>>(ca);

  // 2) fp8 GEMMs, pre-rgate gates: r_h, r_x, u_x, c_x  (2048 blocks x 256 thr, 2 blocks/CU)
  GemmF8 gA = {};
  gA.A[0] = h8; gA.Bw[0] = w8[0]; gA.Y[0] = Y0;   // r_h = h@W_r^T
  gA.A[1] = x8; gA.Bw[1] = w8[1]; gA.Y[1] = Y1;   // r_x = x@U_r^T
  gA.A[2] = x8; gA.Bw[2] = w8[3]; gA.Y[2] = Y3;   // u_x = x@U_u^T
  gA.A[3] = x8; gA.Bw[3] = w8[5]; gA.Y[3] = Y5;   // c_x = x@U_c^T
  gemm_f8s<4><<<2048, 256, 0, stream>>>(gA);

  // 3) r gate: hr = h * sigmoid(LN(r_h)+LN(r_x)), written as fp8
  rgate_kernel<<<2048, 256, 0, stream>>>(Y0, Y1, h, gamma, beta, hr8);

  // 4) fp8 GEMMs, post-rgate gates: u_h, c_h  (1024 blocks)
  GemmF8 gB = {};
  gB.A[0] = h8;  gB.Bw[0] = w8[2]; gB.Y[0] = Y2;  // u_h = h@W_u^T
  gB.A[1] = hr8; gB.Bw[1] = w8[4]; gB.Y[1] = Y0;  // c_h = hr@W_c^T (Y0 reuse)
  gemm_f8s<2><<<1024, 256, 0, stream>>>(gB);

  // 5) u, c, out (h in fp32)
  final_fuse<<<2048, 256, 0, stream>>>(Y2, Y3, Y0, Y5, h, gamma, beta, out);
}

// Round 10
// 240.561 us; speedup vs baseline: 2.9004x; 2.6275x over previous
//
#include <hip/hip_runtime.h>
#include <cstdint>
#include <cstddef>

typedef unsigned short u16;
typedef unsigned char u8;
typedef __attribute__((ext_vector_type(4))) float f32x4;
typedef __attribute__((ext_vector_type(4))) int i32x4;
typedef __attribute__((ext_vector_type(8))) int i32x8;

__device__ inline float bf2f(u16 u) { return __uint_as_float(((unsigned)u) << 16); }
__device__ inline unsigned f2bf(float f) {
  unsigned u = __float_as_uint(f);
  u += 0x7fffu + ((u >> 16) & 1u);   // RNE
  return u >> 16;
}

// f32 -> OCP e4m3fn (RNE). Caller guarantees |f| <= 448.
__device__ inline unsigned f2fp8(float f) {
  unsigned s = (__float_as_uint(f) >> 31) << 7;
  float a = fabsf(f);
  if (a >= 0.015625f) {              // normal range
    unsigned u = __float_as_uint(a);
    u += 0x7FFFFu + ((u >> 20) & 1u);
    unsigned e = (u >> 23) - 120u;   // e32 - 127 + 7
    unsigned m = (u >> 20) & 7u;
    return s | (e << 3) | m;
  }
  int m = (int)rintf(a * 512.0f);    // subnormal step 2^-9 (m=8 rolls to min normal)
  return s | (unsigned)m;
}

__device__ inline void async16(const void* g, void* l) {
  __builtin_amdgcn_global_load_lds(
      (const __attribute__((address_space(1))) void*)g,
      (__attribute__((address_space(3))) void*)l, 16, 0, 0);
}

__device__ inline i32x8 join8(i32x4 lo, i32x4 hi) {
  i32x8 r;
  r[0] = lo[0]; r[1] = lo[1]; r[2] = lo[2]; r[3] = lo[3];
  r[4] = hi[0]; r[5] = hi[1]; r[6] = hi[2]; r[7] = hi[3];
  return r;
}

__device__ inline void unpack8(uint4 q, float* o) {
  o[0] = bf2f((u16)(q.x & 0xffffu)); o[1] = bf2f((u16)(q.x >> 16));
  o[2] = bf2f((u16)(q.y & 0xffffu)); o[3] = bf2f((u16)(q.y >> 16));
  o[4] = bf2f((u16)(q.z & 0xffffu)); o[5] = bf2f((u16)(q.z >> 16));
  o[6] = bf2f((u16)(q.w & 0xffffu)); o[7] = bf2f((u16)(q.w >> 16));
}

__device__ inline float fast_sigmoid(float z) {
  return 1.0f / (1.0f + exp2f(-1.4426950408889634f * z));
}
__device__ inline float fast_tanh(float z) {
  return 1.0f - 2.0f / (1.0f + exp2f(2.8853900817779268f * z));
}

#define SB0() __builtin_amdgcn_sched_barrier(0)

// ---------------- fused convert: x,h -> fp8; all 6 weights -> fp8(x2^13) ----------------
struct ConvArgs3 {
  const float* x; const float* h;
  const float* w[6];                 // W_r, U_r, W_u, U_u, W_c, U_c
  u8* x8; u8* h8;
  u8* w8[6];
};

__global__ __launch_bounds__(256) void convert_all(ConvArgs3 a) {
  const int b = blockIdx.x;
  const int t = threadIdx.x;
  if (b < 16384) {
    const bool isx = b < 8192;
    const int off = isx ? b : b - 8192;
    const float* __restrict__ s = isx ? a.x : a.h;
    u8* __restrict__ d8 = isx ? a.x8 : a.h8;
    const int i = (off * 256 + t) * 4;
    float4 v = *(const float4*)(s + i);
    unsigned q = f2fp8(v.x) | (f2fp8(v.y) << 8) | (f2fp8(v.z) << 16) | (f2fp8(v.w) << 24);
    *(unsigned*)(d8 + i) = q;
  } else {
    const int tt = b - 16384;
    const int which = tt >> 10;      // 0..5
    const int off = tt & 1023;
    const float* __restrict__ s = a.w[which];
    u8* __restrict__ d8 = a.w8[which];
    const int i = (off * 256 + t) * 4;
    float4 v = *(const float4*)(s + i);
    unsigned q = f2fp8(v.x * 8192.f) | (f2fp8(v.y * 8192.f) << 8) |
                 (f2fp8(v.z * 8192.f) << 16) | (f2fp8(v.w * 8192.f) << 24);
    *(unsigned*)(d8 + i) = q;
  }
}

// ---------------- fp8 MX GEMM: Y = A @ W^T, 256x256 tile, BK=128, 8-phase, tail-prefetched ----------------
// Verified schedule (R2/R4/R6 passing). NG gates x 128 blocks each; grid = NG*128 (multiple of 8).
// LDS sm[dbuf][op][half] 128 rows x 128 B fp8, XOR swizzle phys kgroup = logical ^ (row&7).
// vmcnt(6) once per K-tile; never 0 mid-loop. Scales: A = 2^0 (127), W x2^13 -> 2^-13 (114).
// Y output is bf16 (u16): 32B-contiguous fragment stores per 16-lane group — proven clean write
// pattern (R6: WRITE_SIZE == ideal). fp8-Y byte output (R8/R9) caused a pathological 600+ MB
// FETCH/WRITE blowup regardless of store coalescing — do not revisit without a traffic model.
struct GemmF8 { const u8* A[4]; const u8* Bw[4]; u16* Y[4]; };

template <int NG>
__global__ __launch_bounds__(512, 2) void gemm_fp8(GemmF8 args) {
  const int p = blockIdx.x;                       // NG*128 blocks
  const int wg = (p & 7) * (NG * 16) + (p >> 3);  // XCD-contiguous, bijective
  const int gate = wg >> 7;                       // 0..NG-1
  const int rem  = wg & 127;
  const int rblk = rem >> 2;                      // 0..31 (256-row panel)
  const int cblk = rem & 3;                       // 0..3  (256-col panel)

  const u8* __restrict__ A  = args.A[gate];
  const u8* __restrict__ Bw = args.Bw[gate];
  u16* __restrict__ Y = args.Y[gate];

  __shared__ __attribute__((aligned(16))) u8 sm[2][2][2][128 * 128];  // 128 KiB

  const int tid  = threadIdx.x;
  const int lane = tid & 63;
  const int w    = tid >> 6;     // 0..7
  const int wm   = w >> 2;       // 0..1 (M half)
  const int wn   = w & 3;        // 0..3 (N quarter)

  const int l8   = lane >> 3;                 // row within 8-row group == row&7
  const int sgrp = (lane & 7) ^ l8;           // pre-swizzled logical col-group (16B units)
  const u8* aSrc = A  + ((size_t)(rblk * 256 + w * 8 + l8) << 10) + sgrp * 16;
  const u8* bSrc = Bw + ((size_t)(cblk * 256 + w * 8 + l8) << 10) + sgrp * 16;
  const int ldsW = w * 8 * 128;               // wave-uniform LDS base (bytes)

  const int sw = lane & 7;
  const int g0 = (lane >> 4) * 2;
  const int o0 = ((g0 ^ sw) << 4);
  const int o1 = (((g0 + 1) ^ sw) << 4);
  const int frR = (lane & 15) * 128;

  f32x4 acc_lo[4][4] = {};   // m 0..3 x n 0..3
  f32x4 acc_hi[4][4] = {};   // m 4..7 x n 0..3

  auto stage = [&](const u8* src, int tt, int op, int half) {
    const int d = tt & 1;
    const u8* s = src + (size_t)half * 131072 + tt * 128;
    u8* l0 = &sm[d][op][half][ldsW];
    async16(s, l0);                       // rows w*8 .. w*8+7
    async16(s + 65536, l0 + 8192);        // rows +64
  };

  // prologue: B0(0) B1(0) A0(0) A1(0) B0(1) B1(1) A0(1)  (14 loads/thread)
  stage(bSrc, 0, 1, 0); stage(bSrc, 0, 1, 1);
  stage(aSrc, 0, 0, 0); stage(aSrc, 0, 0, 1);
  stage(bSrc, 1, 1, 0); stage(bSrc, 1, 1, 1);
  stage(aSrc, 1, 0, 0);
  asm volatile("s_waitcnt vmcnt(6)" ::: "memory");   // tile 0 landed, 3 halves in flight
  __builtin_amdgcn_s_barrier();

  i32x8 alo[4], bfg[4], ahi[4];
  {  // seed tile 0: alo (8 reads), b01 (4), b23 (4)
    const u8* baseA = &sm[0][0][wm][0];
    const u8* baseB = &sm[0][1][wn >> 1][(wn & 1) * 8192];
#pragma unroll
    for (int m = 0; m < 4; ++m) {
      const int ra = frR + m * 2048;
      alo[m] = join8(*(const i32x4*)&baseA[ra + o0], *(const i32x4*)&baseA[ra + o1]);
    }
#pragma unroll
    for (int n = 0; n < 4; ++n) {
      const int rbb = frR + n * 2048;
      bfg[n] = join8(*(const i32x4*)&baseB[rbb + o0], *(const i32x4*)&baseB[rbb + o1]);
    }
  }
  SB0();

  for (int t = 0; t < 8; ++t) {
    const int d = t & 1;
    const u8* baseA  = &sm[d][0][wm][0];
    const u8* baseA2 = &sm[d ^ 1][0][wm][0];
    const u8* baseB2 = &sm[d ^ 1][1][wn >> 1][(wn & 1) * 8192];

    // ---- P0: stage A1(t+1); MFMA lo x n01 ----
    if (t + 1 < 8) stage(aSrc, t + 1, 0, 1);
    SB0();
    __builtin_amdgcn_s_barrier();
    asm volatile("s_waitcnt lgkmcnt(4)" ::: "memory");
    SB0();
    __builtin_amdgcn_s_setprio(1);
#pragma unroll
    for (int m = 0; m < 4; ++m)
#pragma unroll
      for (int n = 0; n < 2; ++n)
        acc_lo[m][n] = __builtin_amdgcn_mfma_scale_f32_16x16x128_f8f6f4(
            alo[m], bfg[n], acc_lo[m][n], 0, 0, 0, 127, 0, 114);
    __builtin_amdgcn_s_setprio(0);
    SB0();
    __builtin_amdgcn_s_barrier();

    // ---- P1: stage B0(t+2); MFMA lo x n23; tail-read A-hi ----
    if (t + 2 < 8) stage(bSrc, t + 2, 1, 0);
    SB0();
    __builtin_amdgcn_s_barrier();
    asm volatile("s_waitcnt lgkmcnt(0)" ::: "memory");
    SB0();
    __builtin_amdgcn_s_setprio(1);
#pragma unroll
    for (int m = 0; m < 4; ++m)
#pragma unroll
      for (int n = 2; n < 4; ++n)
        acc_lo[m][n] = __builtin_amdgcn_mfma_scale_f32_16x16x128_f8f6f4(
            alo[m], bfg[n], acc_lo[m][n], 0, 0, 0, 127, 0, 114);
    __builtin_amdgcn_s_setprio(0);
    SB0();
#pragma unroll
    for (int m = 0; m < 4; ++m) {
      const int ra = frR + m * 2048 + 8192;
      ahi[m] = join8(*(const i32x4*)&baseA[ra + o0], *(const i32x4*)&baseA[ra + o1]);
    }
    SB0();
    __builtin_amdgcn_s_barrier();

    // ---- P2: stage B1(t+2); MFMA hi x n01 ----
    if (t + 2 < 8) stage(bSrc, t + 2, 1, 1);
    SB0();
    __builtin_amdgcn_s_barrier();
    asm volatile("s_waitcnt lgkmcnt(0)" ::: "memory");
    SB0();
    __builtin_amdgcn_s_setprio(1);
#pragma unroll
    for (int m = 0; m < 4; ++m)
#pragma unroll
      for (int n = 0; n < 2; ++n)
        acc_hi[m][n] = __builtin_amdgcn_mfma_scale_f32_16x16x128_f8f6f4(
            ahi[m], bfg[n], acc_hi[m][n], 0, 0, 0, 127, 0, 114);
    __builtin_amdgcn_s_setprio(0);
    SB0();
    __builtin_amdgcn_s_barrier();

    // ---- P3: stage A0(t+2); MFMA hi x n23; vmcnt; tail-read next alo+bfg ----
    if (t + 2 < 8) stage(aSrc, t + 2, 0, 0);
    SB0();
    __builtin_amdgcn_s_barrier();
    __builtin_amdgcn_s_setprio(1);
#pragma unroll
    for (int m = 0; m < 4; ++m)
#pragma unroll
      for (int n = 2; n < 4; ++n)
        acc_hi[m][n] = __builtin_amdgcn_mfma_scale_f32_16x16x128_f8f6f4(
            ahi[m], bfg[n], acc_hi[m][n], 0, 0, 0, 127, 0, 114);
    __builtin_amdgcn_s_setprio(0);
    SB0();
    if (t < 6) asm volatile("s_waitcnt vmcnt(6)" ::: "memory");
    else       asm volatile("s_waitcnt vmcnt(0)" ::: "memory");
    SB0();
    if (t + 1 < 8) {
#pragma unroll
      for (int m = 0; m < 4; ++m) {
        const int ra = frR + m * 2048;
        alo[m] = join8(*(const i32x4*)&baseA2[ra + o0], *(const i32x4*)&baseA2[ra + o1]);
      }
#pragma unroll
      for (int n = 0; n < 4; ++n) {
        const int rbb = frR + n * 2048;
        bfg[n] = join8(*(const i32x4*)&baseB2[rbb + o0], *(const i32x4*)&baseB2[rbb + o1]);
      }
    }
    SB0();
    __builtin_amdgcn_s_barrier();
  }

  const int rBase = rblk * 256 + wm * 128 + (lane >> 4) * 4;
  const int cBase = cblk * 256 + wn * 64 + (lane & 15);
#pragma unroll
  for (int m = 0; m < 4; ++m) {
#pragma unroll
    for (int i = 0; i < 4; ++i) {
      const size_t r0 = (size_t)(rBase + m * 16 + i) * 1024 + cBase;
#pragma unroll
      for (int n = 0; n < 4; ++n) {
        Y[r0 + n * 16]             = (u16)f2bf(acc_lo[m][n][i]);
        Y[r0 + 64 * 1024 + n * 16] = (u16)f2bf(acc_hi[m][n][i]);
      }
    }
  }
}

// ---------------- r gate: wave-per-row; reads h fp32; writes hr as fp8 ----------------
__global__ __launch_bounds__(256) void rgate_kernel(
    const u16* __restrict__ Yrh, const u16* __restrict__ Yrx,
    const float* __restrict__ h, const float* __restrict__ gamma,
    const float* __restrict__ beta, u8* __restrict__ hr8) {
  const int row  = blockIdx.x * 4 + (threadIdx.x >> 6);
  const int lane = threadIdx.x & 63;
  const size_t rb = (size_t)row * 1024;

  uint4 qa[2], qb[2];
  float4 hf[4];
#pragma unroll
  for (int c = 0; c < 2; c++) {
    const int cb = c * 512 + lane * 8;
    qa[c] = *(const uint4*)(Yrh + rb + cb);
    qb[c] = *(const uint4*)(Yrx + rb + cb);
    hf[c * 2]     = *(const float4*)(h + rb + cb);
    hf[c * 2 + 1] = *(const float4*)(h + rb + cb + 4);
  }

  float s0 = 0.f, s0q = 0.f, s1 = 0.f, s1q = 0.f;
  float tmp[8];
#pragma unroll
  for (int c = 0; c < 2; c++) {
    unpack8(qa[c], tmp);
#pragma unroll
    for (int j = 0; j < 8; j++) { s0 += tmp[j]; s0q += tmp[j] * tmp[j]; }
    unpack8(qb[c], tmp);
#pragma unroll
    for (int j = 0; j < 8; j++) { s1 += tmp[j]; s1q += tmp[j] * tmp[j]; }
  }
#pragma unroll
  for (int off = 1; off < 64; off <<= 1) {
    s0 += __shfl_xor(s0, off, 64);  s0q += __shfl_xor(s0q, off, 64);
    s1 += __shfl_xor(s1, off, 64);  s1q += __shfl_xor(s1q, off, 64);
  }

  const float inv = 1.0f / 1024.0f;
  const float mu0 = s0 * inv, rs0 = rsqrtf(s0q * inv - mu0 * mu0 + 1e-5f);
  const float mu1 = s1 * inv, rs1 = rsqrtf(s1q * inv - mu1 * mu1 + 1e-5f);

#pragma unroll
  for (int c = 0; c < 2; c++) {
    const int cb = c * 512 + lane * 8;
    float va[8], vb[8], o[8];
    unpack8(qa[c], va); unpack8(qb[c], vb);
    const float* hv = (const float*)&hf[c * 2];
#pragma unroll
    for (int j = 0; j < 8; j++) {
      const float ln0 = (va[j] - mu0) * rs0 * gamma[cb + j] + beta[cb + j];
      const float ln1 = (vb[j] - mu1) * rs1 * gamma[1024 + cb + j] + beta[1024 + cb + j];
      const float rg = fast_sigmoid(ln0 + ln1);
      o[j] = hv[j] * rg;
    }
    uint2 q;
    q.x = f2fp8(o[0]) | (f2fp8(o[1]) << 8) | (f2fp8(o[2]) << 16) | (f2fp8(o[3]) << 24);
    q.y = f2fp8(o[4]) | (f2fp8(o[5]) << 8) | (f2fp8(o[6]) << 16) | (f2fp8(o[7]) << 24);
    *(uint2*)(hr8 + rb + cb) = q;
  }
}

// ---------------- final: wave-per-row; h read in fp32 ----------------
__global__ __launch_bounds__(256) void final_fuse(
    const u16* __restrict__ Yuh, const u16* __restrict__ Yux,
    const u16* __restrict__ Ych, const u16* __restrict__ Ycx,
    const float* __restrict__ h, const float* __restrict__ gamma,
    const float* __restrict__ beta, float* __restrict__ out) {
  const int row  = blockIdx.x * 4 + (threadIdx.x >> 6);
  const int lane = threadIdx.x & 63;
  const size_t rb = (size_t)row * 1024;

  uint4 q0[2], q1[2], q2[2], q3[2];
  float4 hf[4];
#pragma unroll
  for (int c = 0; c < 2; c++) {
    const int cb = c * 512 + lane * 8;
    q0[c] = *(const uint4*)(Yuh + rb + cb);
    q1[c] = *(const uint4*)(Yux + rb + cb);
    q2[c] = *(const uint4*)(Ych + rb + cb);
    q3[c] = *(const uint4*)(Ycx + rb + cb);
    hf[c * 2]     = *(const float4*)(h + rb + cb);
    hf[c * 2 + 1] = *(const float4*)(h + rb + cb + 4);
  }

  float s[8] = {0.f, 0.f, 0.f, 0.f, 0.f, 0.f, 0.f, 0.f};
  float tmp[8];
#pragma unroll
  for (int c = 0; c < 2; c++) {
    unpack8(q0[c], tmp);
#pragma unroll
    for (int j = 0; j < 8; j++) { s[0] += tmp[j]; s[1] += tmp[j] * tmp[j]; }
    unpack8(q1[c], tmp);
#pragma unroll
    for (int j = 0; j < 8; j++) { s[2] += tmp[j]; s[3] += tmp[j] * tmp[j]; }
    unpack8(q2[c], tmp);
#pragma unroll
    for (int j = 0; j < 8; j++) { s[4] += tmp[j]; s[5] += tmp[j] * tmp[j]; }
    unpack8(q3[c], tmp);
#pragma unroll
    for (int j = 0; j < 8; j++) { s[6] += tmp[j]; s[7] += tmp[j] * tmp[j]; }
  }
#pragma unroll
  for (int off = 1; off < 64; off <<= 1) {
#pragma unroll
    for (int q = 0; q < 8; q++) s[q] += __shfl_xor(s[q], off, 64);
  }

  const float inv = 1.0f / 1024.0f;
  const float mu0 = s[0] * inv, rs0 = rsqrtf(s[1] * inv - mu0 * mu0 + 1e-5f);
  const float mu1 = s[2] * inv, rs1 = rsqrtf(s[3] * inv - mu1 * mu1 + 1e-5f);
  const float mu2 = s[4] * inv, rs2 = rsqrtf(s[5] * inv - mu2 * mu2 + 1e-5f);
  const float mu3 = s[6] * inv, rs3 = rsqrtf(s[7] * inv - mu3 * mu3 + 1e-5f);

#pragma unroll
  for (int c = 0; c < 2; c++) {
    const int cb = c * 512 + lane * 8;
    float v0[8], v1[8], v2[8], v3[8];
    unpack8(q0[c], v0); unpack8(q1[c], v1); unpack8(q2[c], v2); unpack8(q3[c], v3);
    const float* hv = (const float*)&hf[c * 2];
    float o[8];
#pragma unroll
    for (int j = 0; j < 8; j++) {
      const int cc = cb + j;
      const float ln2 = (v0[j] - mu0) * rs0 * gamma[2 * 1024 + cc] + beta[2 * 1024 + cc];
      const float ln3 = (v1[j] - mu1) * rs1 * gamma[3 * 1024 + cc] + beta[3 * 1024 + cc];
      const float ln4 = (v2[j] - mu2) * rs2 * gamma[4 * 1024 + cc] + beta[4 * 1024 + cc];
      const float ln5 = (v3[j] - mu3) * rs3 * gamma[5 * 1024 + cc] + beta[5 * 1024 + cc];
      const float u  = fast_sigmoid(ln2 + ln3);
      const float cg = fast_tanh(ln4 + ln5);
      o[j] = (1.0f - u) * hv[j] + u * cg;
    }
    *(float4*)(out + rb + cb)     = *(float4*)&o[0];
    *(float4*)(out + rb + cb + 4) = *(float4*)&o[4];
  }
}

extern "C" void kernel_launch(void* const* d_in, const int* in_sizes, int n_in,
                              void* d_out, int out_size, void* d_ws, size_t ws_size,
                              hipStream_t stream) {
  const float* x  = (const float*)d_in[0];
  const float* h  = (const float*)d_in[1];
  const float* W_r = (const float*)d_in[2];
  const float* U_r = (const float*)d_in[3];
  const float* W_u = (const float*)d_in[4];
  const float* U_u = (const float*)d_in[5];
  const float* W_c = (const float*)d_in[6];
  const float* U_c = (const float*)d_in[7];
  const float* gamma = (const float*)d_in[8];
  const float* beta  = (const float*)d_in[9];
  float* out = (float*)d_out;

  char* ws = (char*)d_ws;
  const size_t MB = 1024 * 1024;

  u8* x8  = (u8*)(ws);                        // 8 MiB
  u8* h8  = (u8*)(ws + 8 * MB);               // 8 MiB
  u8* hr8 = (u8*)(ws + 16 * MB);              // 8 MiB
  u8* w8[6];
  for (int i = 0; i < 6; i++) w8[i] = (u8*)(ws + 24 * MB + i * MB);  // 6 MiB
  u16* Y0 = (u16*)(ws + 32 * MB);             // r_hidden -> c_hidden (reused)
  u16* Y1 = (u16*)(ws + 48 * MB);             // r_input (dead after rgate)
  u16* Y2 = (u16*)(ws + 64 * MB);             // u_hidden
  u16* Y3 = (u16*)(ws + 80 * MB);             // u_input
  u16* Y5 = (u16*)(ws + 96 * MB);             // c_input
  // total ws: 112 MiB

  // 1) fused convert: x,h -> fp8; 6 weights -> fp8 x2^13  (16384 + 6144 blocks)
  ConvArgs3 ca = {};
  ca.x = x; ca.h = h;
  ca.w[0] = W_r; ca.w[1] = U_r; ca.w[2] = W_u; ca.w[3] = U_u; ca.w[4] = W_c; ca.w[5] = U_c;
  ca.x8 = x8; ca.h8 = h8;
  for (int i = 0; i < 6; i++) ca.w8[i] = w8[i];
  convert_all<<<22528, 256, 0, stream>>>(ca);

  // 2) fp8 GEMMs, pre-rgate gates: r_h, r_x, u_x, c_x  (512 blocks = 2 CU-rounds)
  GemmF8 gA = {};
  gA.A[0] = h8; gA.Bw[0] = w8[0]; gA.Y[0] = Y0;   // r_h = h@W_r^T
  gA.A[1] = x8; gA.Bw[1] = w8[1]; gA.Y[1] = Y1;   // r_x = x@U_r^T
  gA.A[2] = x8; gA.Bw[2] = w8[3]; gA.Y[2] = Y3;   // u_x = x@U_u^T
  gA.A[3] = x8; gA.Bw[3] = w8[5]; gA.Y[3] = Y5;   // c_x = x@U_c^T
  gemm_fp8<4><<<512, 512, 0, stream>>>(gA);

  // 3) r gate: hr = h * sigmoid(LN(r_h)+LN(r_x)), written as fp8
  rgate_kernel<<<2048, 256, 0, stream>>>(Y0, Y1, h, gamma, beta, hr8);

  // 4) fp8 GEMMs, post-rgate gates: u_h, c_h  (256 blocks = 1 CU-round)
  GemmF8 gB = {};
  gB.A[0] = h8;  gB.Bw[0] = w8[2]; gB.Y[0] = Y2;  // u_h = h@W_u^T
  gB.A[1] = hr8; gB.Bw[1] = w8[4]; gB.Y[1] = Y0;  // c_h = hr@W_c^T (Y0 reuse)
  gemm_fp8<2><<<256, 512, 0, stream>>>(gB);

  // 5) u, c, out (h in fp32)
  final_fuse<<<2048, 256, 0, stream>>>(Y2, Y3, Y0, Y5, h, gamma, beta, out);
}